// Round 8
// baseline (466.986 us; speedup 1.0000x reference)
//
#include <hip/hip_runtime.h>

#define N_NODES 50000
#define N_EDGES 800000
#define DFEAT 64
#define HID 128
#define NBKT 16
#define NPB 3200          // 16*3200=51200>=50000; 3200%64==0 -> fc tile never straddles
#define CAP_C 57344       // per-bucket capacity: mean ~51.2K, sigma ~226 -> +27 sigma
#define QCAP 1536         // per-block edge queue: mean 1024, sigma 32 -> +16 sigma
#define ASTR 68           // LDS acc stride (fp32): 68%32==4 -> b128 reads <=2-way

typedef __bf16 bf16x8 __attribute__((ext_vector_type(8)));
typedef float f32x4 __attribute__((ext_vector_type(4)));

__device__ inline unsigned short f2bf(float f) {   // round-to-nearest-even
  unsigned u = __float_as_uint(f);
  return (unsigned short)((u + 0x7FFFu + ((u >> 16) & 1u)) >> 16);
}
__device__ inline float bf2f(unsigned short h) {
  return __uint_as_float(((unsigned)h) << 16);
}

#define XB_BLOCKS 3125    // N_NODES*DFEAT/4 / 256
#define WB_BLOCKS 16      // HID*2*DFEAT/4 / 256
#define EB_BLOCKS 782     // ceil(N_EDGES/4/256)

// ---------- prep: bf16 convert (x,W) + coarse bin edges by dst/3200 ----------
__global__ __launch_bounds__(256) void k_prep(const float* __restrict__ x,
                                              const float* __restrict__ W,
                                              const int* __restrict__ ei,
                                              unsigned short* __restrict__ xb,
                                              unsigned short* __restrict__ Wb,
                                              int* __restrict__ ccnt,
                                              unsigned int* __restrict__ coarse) {
  int bid = blockIdx.x;
  if (bid < XB_BLOCKS) {                      // x -> bf16
    int t = bid * 256 + threadIdx.x;
    float4 v = *(const float4*)&x[t * 4];
    ushort4 o = {f2bf(v.x), f2bf(v.y), f2bf(v.z), f2bf(v.w)};
    *(ushort4*)&xb[t * 4] = o;
    return;
  }
  bid -= XB_BLOCKS;
  if (bid < WB_BLOCKS) {                      // W -> bf16
    int t = bid * 256 + threadIdx.x;
    float4 v = *(const float4*)&W[t * 4];
    ushort4 o = {f2bf(v.x), f2bf(v.y), f2bf(v.z), f2bf(v.w)};
    *(ushort4*)&Wb[t * 4] = o;
    return;
  }
  bid -= XB_BLOCKS == XB_BLOCKS ? WB_BLOCKS : WB_BLOCKS;  // bid -= WB_BLOCKS
  // coarse binning: 1024 edges per block
  __shared__ int lcnt[NBKT];
  __shared__ int lbase[NBKT];
  const int tid = threadIdx.x;
  if (tid < NBKT) lcnt[tid] = 0;
  __syncthreads();

  int e0 = (bid * 256 + tid) * 4;
  bool valid = e0 < N_EDGES;                  // N_EDGES%4==0: all-or-nothing
  int bkt[4], rank[4];
  unsigned int pk[4];
  if (valid) {
    int4 s4 = *(const int4*)&ei[e0];
    int4 d4 = *(const int4*)&ei[N_EDGES + e0];
    int ss[4] = {s4.x, s4.y, s4.z, s4.w};
    int dd[4] = {d4.x, d4.y, d4.z, d4.w};
#pragma unroll
    for (int i = 0; i < 4; ++i) {
      bkt[i] = dd[i] / NPB;                   // magic-mul
      pk[i] = ((unsigned)dd[i] << 16) | (unsigned)ss[i];
    }
#pragma unroll
    for (int i = 0; i < 4; ++i) rank[i] = atomicAdd(&lcnt[bkt[i]], 1);
  }
  __syncthreads();
  if (tid < NBKT) lbase[tid] = atomicAdd(&ccnt[tid], lcnt[tid]);
  __syncthreads();
  if (valid) {
#pragma unroll
    for (int i = 0; i < 4; ++i) {
      int pos = lbase[bkt[i]] + rank[i];
      if (pos < CAP_C) coarse[bkt[i] * CAP_C + pos] = pk[i];
    }
  }
}

// ---------- fused: scan bucket -> LDS queue -> gather+LDS-acc -> MFMA fc ----------
// Block = 64 nodes. acc[64][ASTR] fp32 neighbor sums; queue of (rel<<16|src).
__global__ __launch_bounds__(256) void k_gnn(const unsigned short* __restrict__ xb,
                                             const unsigned short* __restrict__ Wb,
                                             const unsigned int* __restrict__ coarse,
                                             const int* __restrict__ ccnt,
                                             const float* __restrict__ b,
                                             float* __restrict__ out) {
  __shared__ float acc[64 * ASTR];     // 17408 B
  __shared__ unsigned int queue[QCAP]; // 6144 B
  __shared__ int qn;

  const int tid = threadIdx.x;
  const unsigned nb = blockIdx.x * 64;
  const int wave = tid >> 6;
  const int lane = tid & 63;

  for (int i = tid; i < 64 * ASTR; i += 256) acc[i] = 0.f;
  if (tid == 0) qn = 0;
  __syncthreads();

  // --- scan this block's coarse bucket, compact matches into queue ---
  {
    int bkt = nb / NPB;
    int cnt = ccnt[bkt];
    cnt = cnt < CAP_C ? cnt : CAP_C;
    const unsigned int* cb = &coarse[(size_t)bkt * CAP_C];
    int nv4 = cnt >> 2;
    for (int g = tid; g < nv4; g += 256) {
      uint4 p4 = ((const uint4*)cb)[g];
      unsigned p[4] = {p4.x, p4.y, p4.z, p4.w};
#pragma unroll
      for (int i = 0; i < 4; ++i) {
        unsigned rel = (p[i] >> 16) - nb;
        if (rel < 64u) {
          int q = atomicAdd(&qn, 1);
          if (q < QCAP) queue[q] = (rel << 16) | (p[i] & 0xffffu);
        }
      }
    }
    for (int i = (nv4 << 2) + tid; i < cnt; i += 256) {
      unsigned p = cb[i];
      unsigned rel = (p >> 16) - nb;
      if (rel < 64u) {
        int q = atomicAdd(&qn, 1);
        if (q < QCAP) queue[q] = (rel << 16) | (p & 0xffffu);
      }
    }
  }
  __syncthreads();

  // --- gather + accumulate: wave-per-edge, lane = feature, ILP-4 ---
  {
    int n = qn < QCAP ? qn : QCAP;
    for (int i = wave * 4; i < n; i += 16) {
      unsigned q0 = queue[i];
      int rem = n - i;
      unsigned q1 = rem > 1 ? queue[i + 1] : q0;
      unsigned q2 = rem > 2 ? queue[i + 2] : q0;
      unsigned q3 = rem > 3 ? queue[i + 3] : q0;
      float v0 = bf2f(xb[(q0 & 0xffffu) * DFEAT + lane]);
      float v1 = bf2f(xb[(q1 & 0xffffu) * DFEAT + lane]);
      float v2 = bf2f(xb[(q2 & 0xffffu) * DFEAT + lane]);
      float v3 = bf2f(xb[(q3 & 0xffffu) * DFEAT + lane]);
      atomicAdd(&acc[(q0 >> 16) * ASTR + lane], v0);
      if (rem > 1) atomicAdd(&acc[(q1 >> 16) * ASTR + lane], v1);
      if (rem > 2) atomicAdd(&acc[(q2 >> 16) * ASTR + lane], v2);
      if (rem > 3) atomicAdd(&acc[(q3 >> 16) * ASTR + lane], v3);
    }
  }
  __syncthreads();

  // --- MFMA fc: wave = 16 nodes x 128 outs ---
  const int l15 = lane & 15;
  const int quad = lane >> 4;
  const int node0 = nb + wave * 16;

  int anode = node0 + l15;
  if (anode >= N_NODES) anode = N_NODES - 1;   // clamp; stores guarded
  const unsigned short* hx = xb + (size_t)anode * DFEAT;

  bf16x8 a0 = *(const bf16x8*)(hx + quad * 8);        // k 0..31
  bf16x8 a1 = *(const bf16x8*)(hx + 32 + quad * 8);   // k 32..63
  bf16x8 a2, a3;                                      // k 64..127 from LDS acc
  {
    const float* ar = &acc[(wave * 16 + l15) * ASTR];
#pragma unroll
    for (int j = 0; j < 8; ++j) {
      a2[j] = (__bf16)ar[quad * 8 + j];
      a3[j] = (__bf16)ar[32 + quad * 8 + j];
    }
  }

  f32x4 accr[8];
#pragma unroll
  for (int nt = 0; nt < 8; ++nt) accr[nt] = (f32x4){0.f, 0.f, 0.f, 0.f};

#pragma unroll
  for (int nt = 0; nt < 8; ++nt) {
    const unsigned short* wr = Wb + (size_t)(nt * 16 + l15) * (2 * DFEAT) + quad * 8;
    bf16x8 b0 = *(const bf16x8*)(wr);
    bf16x8 b1 = *(const bf16x8*)(wr + 32);
    bf16x8 b2 = *(const bf16x8*)(wr + 64);
    bf16x8 b3 = *(const bf16x8*)(wr + 96);
    accr[nt] = __builtin_amdgcn_mfma_f32_16x16x32_bf16(a0, b0, accr[nt], 0, 0, 0);
    accr[nt] = __builtin_amdgcn_mfma_f32_16x16x32_bf16(a1, b1, accr[nt], 0, 0, 0);
    accr[nt] = __builtin_amdgcn_mfma_f32_16x16x32_bf16(a2, b2, accr[nt], 0, 0, 0);
    accr[nt] = __builtin_amdgcn_mfma_f32_16x16x32_bf16(a3, b3, accr[nt], 0, 0, 0);
  }

  // epilogue: D[m=quad*4+r][n=nt*16+l15]
#pragma unroll
  for (int nt = 0; nt < 8; ++nt) {
    float bias = b[nt * 16 + l15];
#pragma unroll
    for (int r = 0; r < 4; ++r) {
      int node = node0 + quad * 4 + r;
      if (node < N_NODES) {
        float v = accr[nt][r] + bias;
        out[(size_t)node * HID + nt * 16 + l15] = v > 0.f ? v : 0.f;
      }
    }
  }
}

extern "C" void kernel_launch(void* const* d_in, const int* in_sizes, int n_in,
                              void* d_out, int out_size, void* d_ws, size_t ws_size,
                              hipStream_t stream) {
  const float* x = (const float*)d_in[0];
  const int* ei = (const int*)d_in[1];
  const float* W = (const float*)d_in[2];
  const float* b = (const float*)d_in[3];
  float* out = (float*)d_out;

  // workspace layout (~10.2 MB), 256B-aligned regions
  char* ws = (char*)d_ws;
  int* ccnt               = (int*)ws;             ws += 256;
  unsigned int* coarse    = (unsigned int*)ws;    ws += (size_t)NBKT * CAP_C * 4;
  unsigned short* xb      = (unsigned short*)ws;  ws += (size_t)N_NODES * DFEAT * 2;
  unsigned short* Wb      = (unsigned short*)ws;  ws += (size_t)HID * 2 * DFEAT * 2;

  hipMemsetAsync(ccnt, 0, NBKT * sizeof(int), stream);

  k_prep<<<XB_BLOCKS + WB_BLOCKS + EB_BLOCKS, 256, 0, stream>>>(
      x, W, ei, xb, Wb, ccnt, coarse);
  k_gnn<<<(N_NODES + 63) / 64, 256, 0, stream>>>(xb, Wb, coarse, ccnt, b, out);
}

// Round 10
// 183.879 us; speedup vs baseline: 2.5396x; 2.5396x over previous
//
#include <hip/hip_runtime.h>

#define N_NODES 50000
#define N_EDGES 800000
#define DFEAT 64
#define HID 128
#define CAP 64        // per-dst bucket capacity; P(deg>=64) ~1e-19
#define NBKT 16
#define NPB 3125      // nodes per coarse bucket
#define CAP_C 53248   // coarse capacity (+15 sigma)
#define CHUNK 1024
#define NCHUNK (CAP_C / CHUNK)   // 52
#define NSTR 65       // LDS ns stride: pull writes 2-way, fc b128 reads <=2-way

#define XB_BLOCKS 3125    // N_NODES*DFEAT/4 / 256
#define WB_BLOCKS 16      // HID*2*DFEAT/4 / 256
#define EB_BLOCKS 782     // ceil(N_EDGES/4/256)

typedef __bf16 bf16x8 __attribute__((ext_vector_type(8)));
typedef float f32x4 __attribute__((ext_vector_type(4)));

__device__ inline unsigned short f2bf(float f) {   // round-to-nearest-even
  unsigned u = __float_as_uint(f);
  return (unsigned short)((u + 0x7FFFu + ((u >> 16) & 1u)) >> 16);
}
__device__ inline float bf2f(unsigned short h) {
  return __uint_as_float(((unsigned)h) << 16);
}

// ---------- prep: bf16 convert (x,W) + zero cursor + coarse bin by dst/3125 ----------
__global__ __launch_bounds__(256) void k_prep(const float* __restrict__ x,
                                              const float* __restrict__ W,
                                              const int* __restrict__ ei,
                                              unsigned short* __restrict__ xb,
                                              unsigned short* __restrict__ Wb,
                                              int* __restrict__ cursor,
                                              int* __restrict__ ccnt,
                                              unsigned int* __restrict__ coarse) {
  int bid = blockIdx.x;
  if (bid < XB_BLOCKS) {                      // x -> bf16, piggyback cursor zero
    int t = bid * 256 + threadIdx.x;
    float4 v = *(const float4*)&x[t * 4];
    ushort4 o = {f2bf(v.x), f2bf(v.y), f2bf(v.z), f2bf(v.w)};
    *(ushort4*)&xb[t * 4] = o;
    if (t < N_NODES) cursor[t] = 0;
    return;
  }
  bid -= XB_BLOCKS;
  if (bid < WB_BLOCKS) {                      // W -> bf16
    int t = bid * 256 + threadIdx.x;
    float4 v = *(const float4*)&W[t * 4];
    ushort4 o = {f2bf(v.x), f2bf(v.y), f2bf(v.z), f2bf(v.w)};
    *(ushort4*)&Wb[t * 4] = o;
    return;
  }
  bid -= WB_BLOCKS;
  // coarse binning: 1024 edges per block, LDS hist + contiguous packed writes
  __shared__ int lcnt[NBKT];
  __shared__ int lbase[NBKT];
  const int tid = threadIdx.x;
  if (tid < NBKT) lcnt[tid] = 0;
  __syncthreads();

  int e0 = (bid * 256 + tid) * 4;
  bool valid = e0 < N_EDGES;                  // N_EDGES%4==0: all-or-nothing
  int bkt[4], rank[4];
  unsigned int pk[4];
  if (valid) {
    int4 s4 = *(const int4*)&ei[e0];
    int4 d4 = *(const int4*)&ei[N_EDGES + e0];
    int ss[4] = {s4.x, s4.y, s4.z, s4.w};
    int dd[4] = {d4.x, d4.y, d4.z, d4.w};
#pragma unroll
    for (int i = 0; i < 4; ++i) {
      bkt[i] = dd[i] / NPB;                   // magic-mul
      pk[i] = ((unsigned)dd[i] << 16) | (unsigned)ss[i];
    }
#pragma unroll
    for (int i = 0; i < 4; ++i) rank[i] = atomicAdd(&lcnt[bkt[i]], 1);
  }
  __syncthreads();
  if (tid < NBKT) lbase[tid] = atomicAdd(&ccnt[tid], lcnt[tid]);
  __syncthreads();
  if (valid) {
#pragma unroll
    for (int i = 0; i < 4; ++i) {
      int pos = lbase[bkt[i]] + rank[i];
      if (pos < CAP_C) coarse[bkt[i] * CAP_C + pos] = pk[i];
    }
  }
}

// ---------- fine: scatter one bucket-chunk into per-node srclist ----------
__global__ __launch_bounds__(256) void k_fine(const unsigned int* __restrict__ coarse,
                                              const int* __restrict__ ccnt,
                                              int* __restrict__ cursor,
                                              unsigned short* __restrict__ srclist) {
  int b = blockIdx.x & (NBKT - 1);
  int chunk = blockIdx.x >> 4;
  int cnt = ccnt[b];
  cnt = cnt < CAP_C ? cnt : CAP_C;
  const unsigned int* cb = &coarse[(size_t)b * CAP_C];
  int base = chunk * CHUNK;
#pragma unroll
  for (int it = 0; it < 4; ++it) {
    int idx = base + it * 256 + threadIdx.x;
    if (idx < cnt) {
      unsigned int p = cb[idx];
      int d = (int)(p >> 16);
      int s = (int)(p & 0xffffu);
      int pos = atomicAdd(&cursor[d], 1);
      if (pos < CAP) srclist[d * CAP + pos] = (unsigned short)s;
    }
  }
}

// ---------- fused pull + MFMA fc per 64-node tile ----------
__global__ __launch_bounds__(256) void k_pullfc(const unsigned short* __restrict__ xb,
                                                const unsigned short* __restrict__ Wb,
                                                const int* __restrict__ cursor,
                                                const unsigned short* __restrict__ srclist,
                                                const float* __restrict__ bv,
                                                float* __restrict__ out) {
  __shared__ float ns[64 * NSTR];   // 16.6 KB fp32 neighbor sums

  const int tid = threadIdx.x;
  const int nb = blockIdx.x * 64;
  const int wave = tid >> 6;
  const int lane = tid & 63;

  // pull: wave handles nodes nb+wave*16 .. +15, lane = feature
  for (int i = 0; i < 16; ++i) {
    int n = wave * 16 + i;
    int node = nb + n;
    float a0 = 0.f, a1 = 0.f, a2 = 0.f, a3 = 0.f;
    if (node < N_NODES) {
      int cnt = cursor[node];
      cnt = cnt < CAP ? cnt : CAP;
      int myent = (lane < cnt) ? (int)srclist[node * CAP + lane] : 0;
      int j = 0;
      for (; j + 3 < cnt; j += 4) {
        int s0 = __shfl(myent, j);
        int s1 = __shfl(myent, j + 1);
        int s2 = __shfl(myent, j + 2);
        int s3 = __shfl(myent, j + 3);
        a0 += bf2f(xb[s0 * DFEAT + lane]);
        a1 += bf2f(xb[s1 * DFEAT + lane]);
        a2 += bf2f(xb[s2 * DFEAT + lane]);
        a3 += bf2f(xb[s3 * DFEAT + lane]);
      }
      for (; j < cnt; ++j) {
        int s = __shfl(myent, j);
        a0 += bf2f(xb[s * DFEAT + lane]);
      }
    }
    ns[n * NSTR + lane] = (a0 + a1) + (a2 + a3);
  }
  __syncthreads();

  // fc: wave = 16 nodes x 128 outs via mfma 16x16x32 bf16
  const int l15 = lane & 15;
  const int quad = lane >> 4;
  const int node0 = nb + wave * 16;

  int anode = node0 + l15;
  if (anode >= N_NODES) anode = N_NODES - 1;   // clamp; stores guarded
  const unsigned short* hx = xb + (size_t)anode * DFEAT;

  bf16x8 fa0 = *(const bf16x8*)(hx + quad * 8);        // k 0..31
  bf16x8 fa1 = *(const bf16x8*)(hx + 32 + quad * 8);   // k 32..63
  bf16x8 fa2, fa3;                                     // k 64..127 from LDS
  {
    const float* ar = &ns[(wave * 16 + l15) * NSTR];
#pragma unroll
    for (int j = 0; j < 8; ++j) {
      fa2[j] = (__bf16)ar[quad * 8 + j];
      fa3[j] = (__bf16)ar[32 + quad * 8 + j];
    }
  }

  f32x4 accr[8];
#pragma unroll
  for (int nt = 0; nt < 8; ++nt) accr[nt] = (f32x4){0.f, 0.f, 0.f, 0.f};

#pragma unroll
  for (int nt = 0; nt < 8; ++nt) {
    const unsigned short* wr = Wb + (size_t)(nt * 16 + l15) * (2 * DFEAT) + quad * 8;
    bf16x8 b0 = *(const bf16x8*)(wr);
    bf16x8 b1 = *(const bf16x8*)(wr + 32);
    bf16x8 b2 = *(const bf16x8*)(wr + 64);
    bf16x8 b3 = *(const bf16x8*)(wr + 96);
    accr[nt] = __builtin_amdgcn_mfma_f32_16x16x32_bf16(fa0, b0, accr[nt], 0, 0, 0);
    accr[nt] = __builtin_amdgcn_mfma_f32_16x16x32_bf16(fa1, b1, accr[nt], 0, 0, 0);
    accr[nt] = __builtin_amdgcn_mfma_f32_16x16x32_bf16(fa2, b2, accr[nt], 0, 0, 0);
    accr[nt] = __builtin_amdgcn_mfma_f32_16x16x32_bf16(fa3, b3, accr[nt], 0, 0, 0);
  }

  // epilogue: D[m=quad*4+r][n=nt*16+l15]
#pragma unroll
  for (int nt = 0; nt < 8; ++nt) {
    float bias = bv[nt * 16 + l15];
#pragma unroll
    for (int r = 0; r < 4; ++r) {
      int node = node0 + quad * 4 + r;
      if (node < N_NODES) {
        float v = accr[nt][r] + bias;
        out[(size_t)node * HID + nt * 16 + l15] = v > 0.f ? v : 0.f;
      }
    }
  }
}

extern "C" void kernel_launch(void* const* d_in, const int* in_sizes, int n_in,
                              void* d_out, int out_size, void* d_ws, size_t ws_size,
                              hipStream_t stream) {
  const float* x = (const float*)d_in[0];
  const int* ei = (const int*)d_in[1];
  const float* W = (const float*)d_in[2];
  const float* b = (const float*)d_in[3];
  float* out = (float*)d_out;

  // workspace layout (~16.5 MB), 256B-aligned regions
  char* ws = (char*)d_ws;
  int* ccnt               = (int*)ws;             ws += 256;
  unsigned int* coarse    = (unsigned int*)ws;    ws += (size_t)NBKT * CAP_C * 4;
  unsigned short* xb      = (unsigned short*)ws;  ws += (size_t)N_NODES * DFEAT * 2;
  unsigned short* Wb      = (unsigned short*)ws;  ws += (size_t)HID * 2 * DFEAT * 2;
  int* cursor             = (int*)ws;             ws += ((size_t)N_NODES * 4 + 255) / 256 * 256;
  unsigned short* srclist = (unsigned short*)ws;  ws += (size_t)N_NODES * CAP * 2;

  hipMemsetAsync(ccnt, 0, NBKT * sizeof(int), stream);

  k_prep<<<XB_BLOCKS + WB_BLOCKS + EB_BLOCKS, 256, 0, stream>>>(
      x, W, ei, xb, Wb, cursor, ccnt, coarse);
  k_fine<<<NBKT * NCHUNK, 256, 0, stream>>>(coarse, ccnt, cursor, srclist);
  k_pullfc<<<(N_NODES + 63) / 64, 256, 0, stream>>>(xb, Wb, cursor, srclist, b, out);
}